// Round 8
// baseline (443.131 us; speedup 1.0000x reference)
//
#include <hip/hip_runtime.h>
#include <hip/hip_bf16.h>

// Problem shapes (fixed by reference setup_inputs):
//   B=2048, L=50, D=64, NI=100000, NU=100000
// out = scores (B, NI) fp32.
// ws layout (MFMA path): [item_bf16: NI*64*2][pooled_bf16: B*64*2]
// ws layout (fallback):  [pooled_f32: B*64*4]

#define L_SEQ 50
#define D_EMB 64
#define SHORT_LEN 10
#define LS_LEN 11
#define NEG_INF_F (-1000000000.0f)
#define STRIP_TILES 16
#define STRIP_I 256  // items per wave strip (16 tiles x 16)

typedef __bf16 bf16x8 __attribute__((ext_vector_type(8)));
typedef float f32x4 __attribute__((ext_vector_type(4)));

__device__ __forceinline__ float wave_sum(float v) {
#pragma unroll
  for (int off = 32; off > 0; off >>= 1) v += __shfl_xor(v, off, 64);
  return v;
}
__device__ __forceinline__ float wave_max(float v) {
#pragma unroll
  for (int off = 32; off > 0; off >>= 1) v = fmaxf(v, __shfl_xor(v, off, 64));
  return v;
}

// One 64-thread wave per batch row. lane = output channel e (and d index).
__global__ __launch_bounds__(64) void pool_kernel(
    const int* __restrict__ seq, const int* __restrict__ user_id,
    const float* __restrict__ item_emb, const float* __restrict__ user_emb,
    const float* __restrict__ w1, const float* __restrict__ w1b, const float* __restrict__ b1,
    const float* __restrict__ w2, const float* __restrict__ w2b, const float* __restrict__ b2,
    float* __restrict__ pooled_f32, __bf16* __restrict__ pooled_bf) {
  const int b = blockIdx.x;
  const int lane = threadIdx.x;  // 0..63

  __shared__ float e_lds[L_SEQ][D_EMB];   // gathered item rows
  __shared__ float ls_lds[LS_LEN][D_EMB]; // [long_term, last 10 rows]
  __shared__ float a_lds[D_EMB];          // softmax weights (reused)
  __shared__ int seq_lds[L_SEQ];

  if (lane < L_SEQ) seq_lds[lane] = seq[b * L_SEQ + lane];
  const float u = user_emb[(long)user_id[b] * D_EMB + lane];
  __syncthreads();

  // gather e rows (coalesced 256B per row)
  for (int l = 0; l < L_SEQ; ++l) {
    e_lds[l][lane] = item_emb[(long)seq_lds[l] * D_EMB + lane];
  }

  // preload w1 row for this lane (w[e][d], e = lane)
  float4 w1r[16];
#pragma unroll
  for (int k = 0; k < 16; ++k) w1r[k] = *(const float4*)&w1[lane * D_EMB + 4 * k];
  const float bias1 = w1b[lane] + b1[lane];
  __syncthreads();

  // ---- stage 1: h = relu(e @ w1^T + bias); s[l] = <h[l], u>; mask; softmax over L ----
  float s_val = 0.0f;
  for (int l = 0; l < L_SEQ; ++l) {
    float acc = bias1;
#pragma unroll
    for (int k = 0; k < 16; ++k) {
      float4 ev = *(const float4*)&e_lds[l][4 * k];  // broadcast read
      acc = fmaf(ev.x, w1r[k].x, acc);
      acc = fmaf(ev.y, w1r[k].y, acc);
      acc = fmaf(ev.z, w1r[k].z, acc);
      acc = fmaf(ev.w, w1r[k].w, acc);
    }
    acc = fmaxf(acc, 0.0f);
    float t = wave_sum(acc * u);
    if (lane == l) s_val = (seq_lds[l] == 0) ? NEG_INF_F : t;
  }
  {
    float x = (lane < L_SEQ) ? s_val : -INFINITY;
    float m = wave_max(x);
    float p = (lane < L_SEQ) ? __expf(x - m) : 0.0f;
    float ps = wave_sum(p);
    a_lds[lane] = p / ps;
  }
  __syncthreads();

  // long_term[d] = sum_l a[l] * e[l][d]
  float lt = 0.0f;
  for (int l = 0; l < L_SEQ; ++l) lt = fmaf(a_lds[l], e_lds[l][lane], lt);
  __syncthreads();

  // ---- stage 2: ls = [long_term, e[-10:]] ----
  ls_lds[0][lane] = lt;
#pragma unroll
  for (int j = 1; j < LS_LEN; ++j)
    ls_lds[j][lane] = e_lds[L_SEQ - SHORT_LEN + (j - 1)][lane];

  float4 w2r[16];
#pragma unroll
  for (int k = 0; k < 16; ++k) w2r[k] = *(const float4*)&w2[lane * D_EMB + 4 * k];
  const float bias2 = w2b[lane] + b2[lane];
  __syncthreads();

  float s2_val = 0.0f;
  for (int j = 0; j < LS_LEN; ++j) {
    float acc = bias2;
#pragma unroll
    for (int k = 0; k < 16; ++k) {
      float4 lv = *(const float4*)&ls_lds[j][4 * k];
      acc = fmaf(lv.x, w2r[k].x, acc);
      acc = fmaf(lv.y, w2r[k].y, acc);
      acc = fmaf(lv.z, w2r[k].z, acc);
      acc = fmaf(lv.w, w2r[k].w, acc);
    }
    acc = fmaxf(acc, 0.0f);
    float t = wave_sum(acc * u);
    bool msk = (j == 0) ? false : (seq_lds[L_SEQ - SHORT_LEN + (j - 1)] == 0);
    if (lane == j) s2_val = msk ? NEG_INF_F : t;
  }
  {
    float x = (lane < LS_LEN) ? s2_val : -INFINITY;
    float m = wave_max(x);
    float p = (lane < LS_LEN) ? __expf(x - m) : 0.0f;
    float ps = wave_sum(p);
    __syncthreads();  // a_lds reuse
    a_lds[lane] = p / ps;
  }
  __syncthreads();

  float po = 0.0f;
#pragma unroll
  for (int j = 0; j < LS_LEN; ++j) po = fmaf(a_lds[j], ls_lds[j][lane], po);
  if (pooled_f32) pooled_f32[(long)b * D_EMB + lane] = po;
  if (pooled_bf) pooled_bf[(long)b * D_EMB + lane] = (__bf16)po;
}

// fp32 -> bf16, 8 elements per thread, 16B stores.
__global__ __launch_bounds__(256) void cvt_bf16_kernel(
    const float* __restrict__ in, __bf16* __restrict__ out, int n8) {
  int i = blockIdx.x * blockDim.x + threadIdx.x;
  if (i >= n8) return;
  float4 a = ((const float4*)in)[2 * i];
  float4 b = ((const float4*)in)[2 * i + 1];
  bf16x8 v;
  v[0] = (__bf16)a.x; v[1] = (__bf16)a.y; v[2] = (__bf16)a.z; v[3] = (__bf16)a.w;
  v[4] = (__bf16)b.x; v[5] = (__bf16)b.y; v[6] = (__bf16)b.z; v[7] = (__bf16)b.w;
  ((bf16x8*)out)[i] = v;
}

// MFMA scores, UNCONFOUNDED contiguity test (r7 minus the barrier):
//   Wave = 16 batch rows x 256 items (16 tiles). acc -> wave-PRIVATE 16KB
//   LDS region (stage[w]) -> drain 16 independent 1KB-contiguous dwordx4
//   store instructions (one per row). NO __syncthreads anywhere: same-wave
//   ds_write -> ds_read ordering is guaranteed by compiler waitcnt, so the
//   4 waves free-run and their loads/MFMA/LDS/stores overlap (r7's barrier
//   forced lockstep phases -> latency exposed -> 415us; this isolates it).
//   vs r4 (same free-running, 64B/row scattered stores): isolates
//   per-instruction store contiguity.
// LDS swizzle (verified balanced): granule gp = g ^ (row&7); write = 2
// lanes/bank (free), b128 drain read = exactly 8 accesses/bank (floor).
// C/D map (HW-verified): col = lane&15 (batch), row = 4*(lane>>4)+reg (item).
__global__ __launch_bounds__(256) void scores_mfma_kernel(
    const __bf16* __restrict__ pooled_bf,  // [B][64]
    const __bf16* __restrict__ item_bf,    // [NI][64]
    float* __restrict__ out, int NI, int n_tiles, int n_bgrp) {
  __shared__ __align__(16) float stage[4][16][STRIP_I];  // 64KB, 16KB/wave

  const int bid = blockIdx.x;
  const int strip = bid / n_bgrp;   // consecutive bids share strip -> L2 reuse
  const int bq = bid % n_bgrp;
  const int tid = threadIdx.x;
  const int w = tid >> 6;
  const int l = tid & 63;
  const int lr = l & 15;   // A: item row in tile / B: batch col / C: col
  const int lg = l >> 4;   // k-chunk (8 elems) / C row-group
  const int b0 = (bq * 4 + w) * 16;  // this wave's 16 batch rows

  const int t0 = strip * STRIP_TILES;
  const int tl_cnt = min(STRIP_TILES, n_tiles - t0);
  const int i0 = t0 * 16;
  const int ilen = min(STRIP_I, NI - i0);  // multiple of 16

  // B-operand (pooled) fragment: 16 batch rows x 2 k-halves.
  const __bf16* prow = pooled_bf + (size_t)(b0 + lr) * D_EMB + 8 * lg;
  bf16x8 pf0 = *(const bf16x8*)(prow);
  bf16x8 pf1 = *(const bf16x8*)(prow + 32);

  float(*st)[STRIP_I] = stage[w];

  // ---- compute: 16 tiles -> acc -> swizzled wave-private LDS ----
#pragma unroll 8
  for (int tt = 0; tt < tl_cnt; ++tt) {
    const __bf16* brow = item_bf + (size_t)((t0 + tt) * 16 + lr) * D_EMB + 8 * lg;
    bf16x8 a0 = *(const bf16x8*)(brow);
    bf16x8 a1 = *(const bf16x8*)(brow + 32);
    f32x4 acc = {0.f, 0.f, 0.f, 0.f};
    acc = __builtin_amdgcn_mfma_f32_16x16x32_bf16(a0, pf0, acc, 0, 0, 0);
    acc = __builtin_amdgcn_mfma_f32_16x16x32_bf16(a1, pf1, acc, 0, 0, 0);
    // acc regs q=0..3 = items (t0+tt)*16 + 4*lg + q of batch row lr.
    const int gp = (tt * 4 + lg) ^ (lr & 7);  // 16B granule swizzle
    *(f32x4*)&st[lr][gp * 4] = acc;
  }
  // NO barrier: stage[w] is wave-private; compiler inserts lgkmcnt before
  // the dependent ds_reads below. Waves proceed independently.

  // ---- drain: 16 independent 1KB-contiguous store instrs (one per row) ----
  const bool full = (4 * l < ilen);
#pragma unroll 16
  for (int r = 0; r < 16; ++r) {
    if (full) {
      const int gp = l ^ (r & 7);
      f32x4 v = *(const f32x4*)&st[r][gp * 4];
      *(f32x4*)&out[(size_t)(b0 + r) * NI + i0 + 4 * l] = v;
    }
  }
}

// ---------- fallback fp32 scores (round-1 kernel), used if ws too small ----------
__global__ __launch_bounds__(256) void scores_kernel(
    const float* __restrict__ pooled, const float* __restrict__ item_emb,
    float* __restrict__ out, int NI) {
  constexpr int STR = 68;
  __shared__ __align__(16) float poolT[64 * STR];
  __shared__ __align__(16) float itemT[64 * STR];

  const int tid = threadIdx.x;
  const int lane = tid & 63;
  const int b0 = blockIdx.x * 64;
  const int i0 = blockIdx.y * 64;

  for (int r = tid >> 6; r < 64; r += 4) {
    poolT[lane * STR + r] = pooled[(long)(b0 + r) * D_EMB + lane];
    int i = i0 + r;
    itemT[lane * STR + r] = (i < NI) ? item_emb[(long)i * D_EMB + lane] : 0.0f;
  }
  __syncthreads();

  const int tx = tid & 15;
  const int ty = tid >> 4;
  float acc[4][4] = {};

#pragma unroll 8
  for (int d = 0; d < 64; ++d) {
    float4 pv = *(const float4*)&poolT[d * STR + ty * 4];
    float4 iv = *(const float4*)&itemT[d * STR + tx * 4];
    float pva[4] = {pv.x, pv.y, pv.z, pv.w};
    float iva[4] = {iv.x, iv.y, iv.z, iv.w};
#pragma unroll
    for (int m = 0; m < 4; ++m)
#pragma unroll
      for (int n = 0; n < 4; ++n) acc[m][n] = fmaf(pva[m], iva[n], acc[m][n]);
  }

  const int ibase = i0 + tx * 4;
  const long orow = (long)(b0 + ty * 4);
  if (i0 + 63 < NI) {
#pragma unroll
    for (int m = 0; m < 4; ++m) {
      float4 v = make_float4(acc[m][0], acc[m][1], acc[m][2], acc[m][3]);
      *(float4*)&out[(orow + m) * (long)NI + ibase] = v;
    }
  } else {
#pragma unroll
    for (int m = 0; m < 4; ++m)
#pragma unroll
      for (int n = 0; n < 4; ++n)
        if (ibase + n < NI) out[(orow + m) * (long)NI + ibase + n] = acc[m][n];
  }
}

extern "C" void kernel_launch(void* const* d_in, const int* in_sizes, int n_in,
                              void* d_out, int out_size, void* d_ws, size_t ws_size,
                              hipStream_t stream) {
  const int* seq = (const int*)d_in[0];
  const int* user_id = (const int*)d_in[1];
  const float* item_emb = (const float*)d_in[2];
  const float* user_emb = (const float*)d_in[3];
  const float* w1 = (const float*)d_in[4];
  const float* w1b = (const float*)d_in[5];
  const float* b1 = (const float*)d_in[6];
  const float* w2 = (const float*)d_in[7];
  const float* w2b = (const float*)d_in[8];
  const float* b2 = (const float*)d_in[9];
  float* out = (float*)d_out;

  const int B = in_sizes[1];           // 2048
  const int NI = in_sizes[2] / D_EMB;  // 100000

  const size_t item_bf_bytes = (size_t)NI * D_EMB * 2;
  const size_t pooled_bf_bytes = (size_t)B * D_EMB * 2;
  const bool mfma_ok = (ws_size >= item_bf_bytes + pooled_bf_bytes) &&
                       (NI % 16 == 0) && (B % 64 == 0) && (D_EMB == 64);

  if (mfma_ok) {
    __bf16* item_bf = (__bf16*)d_ws;
    __bf16* pooled_bf = (__bf16*)((char*)d_ws + item_bf_bytes);

    const int n8 = NI * D_EMB / 8;
    cvt_bf16_kernel<<<(n8 + 255) / 256, 256, 0, stream>>>(item_emb, item_bf, n8);

    pool_kernel<<<B, 64, 0, stream>>>(seq, user_id, item_emb, user_emb,
                                      w1, w1b, b1, w2, w2b, b2,
                                      (float*)nullptr, pooled_bf);

    const int n_tiles = NI / 16;                                    // 6250
    const int n_strips = (n_tiles + STRIP_TILES - 1) / STRIP_TILES; // 391
    const int n_bgrp = B / 64;                                      // 32
    scores_mfma_kernel<<<n_strips * n_bgrp, 256, 0, stream>>>(
        pooled_bf, item_bf, out, NI, n_tiles, n_bgrp);
  } else {
    float* pooled = (float*)d_ws;  // B * 64 floats
    pool_kernel<<<B, 64, 0, stream>>>(seq, user_id, item_emb, user_emb,
                                      w1, w1b, b1, w2, w2b, b2,
                                      pooled, (__bf16*)nullptr);
    dim3 grid(B / 64, (NI + 63) / 64);
    scores_kernel<<<grid, 256, 0, stream>>>(pooled, item_emb, out, NI);
  }
}

// Round 9
// 272.835 us; speedup vs baseline: 1.6242x; 1.6242x over previous
//
#include <hip/hip_runtime.h>
#include <hip/hip_bf16.h>

// Problem shapes (fixed by reference setup_inputs):
//   B=2048, L=50, D=64, NI=100000, NU=100000
// out = scores (B, NI) fp32.
// ws layout (MFMA path): [item_bf16: NI*64*2][pooled_bf16: B*64*2]
// ws layout (fallback):  [pooled_f32: B*64*4]

#define L_SEQ 50
#define D_EMB 64
#define SHORT_LEN 10
#define LS_LEN 11
#define NEG_INF_F (-1000000000.0f)
#define N_QUARTERS 4  // item-axis split; blocks = N_QUARTERS * B/16

typedef __bf16 bf16x8 __attribute__((ext_vector_type(8)));
typedef float f32x4 __attribute__((ext_vector_type(4)));

__device__ __forceinline__ float wave_sum(float v) {
#pragma unroll
  for (int off = 32; off > 0; off >>= 1) v += __shfl_xor(v, off, 64);
  return v;
}
__device__ __forceinline__ float wave_max(float v) {
#pragma unroll
  for (int off = 32; off > 0; off >>= 1) v = fmaxf(v, __shfl_xor(v, off, 64));
  return v;
}

// One 64-thread wave per batch row. lane = output channel e (and d index).
__global__ __launch_bounds__(64) void pool_kernel(
    const int* __restrict__ seq, const int* __restrict__ user_id,
    const float* __restrict__ item_emb, const float* __restrict__ user_emb,
    const float* __restrict__ w1, const float* __restrict__ w1b, const float* __restrict__ b1,
    const float* __restrict__ w2, const float* __restrict__ w2b, const float* __restrict__ b2,
    float* __restrict__ pooled_f32, __bf16* __restrict__ pooled_bf) {
  const int b = blockIdx.x;
  const int lane = threadIdx.x;  // 0..63

  __shared__ float e_lds[L_SEQ][D_EMB];   // gathered item rows
  __shared__ float ls_lds[LS_LEN][D_EMB]; // [long_term, last 10 rows]
  __shared__ float a_lds[D_EMB];          // softmax weights (reused)
  __shared__ int seq_lds[L_SEQ];

  if (lane < L_SEQ) seq_lds[lane] = seq[b * L_SEQ + lane];
  const float u = user_emb[(long)user_id[b] * D_EMB + lane];
  __syncthreads();

  // gather e rows (coalesced 256B per row)
  for (int l = 0; l < L_SEQ; ++l) {
    e_lds[l][lane] = item_emb[(long)seq_lds[l] * D_EMB + lane];
  }

  // preload w1 row for this lane (w[e][d], e = lane)
  float4 w1r[16];
#pragma unroll
  for (int k = 0; k < 16; ++k) w1r[k] = *(const float4*)&w1[lane * D_EMB + 4 * k];
  const float bias1 = w1b[lane] + b1[lane];
  __syncthreads();

  // ---- stage 1: h = relu(e @ w1^T + bias); s[l] = <h[l], u>; mask; softmax over L ----
  float s_val = 0.0f;
  for (int l = 0; l < L_SEQ; ++l) {
    float acc = bias1;
#pragma unroll
    for (int k = 0; k < 16; ++k) {
      float4 ev = *(const float4*)&e_lds[l][4 * k];  // broadcast read
      acc = fmaf(ev.x, w1r[k].x, acc);
      acc = fmaf(ev.y, w1r[k].y, acc);
      acc = fmaf(ev.z, w1r[k].z, acc);
      acc = fmaf(ev.w, w1r[k].w, acc);
    }
    acc = fmaxf(acc, 0.0f);
    float t = wave_sum(acc * u);
    if (lane == l) s_val = (seq_lds[l] == 0) ? NEG_INF_F : t;
  }
  {
    float x = (lane < L_SEQ) ? s_val : -INFINITY;
    float m = wave_max(x);
    float p = (lane < L_SEQ) ? __expf(x - m) : 0.0f;
    float ps = wave_sum(p);
    a_lds[lane] = p / ps;
  }
  __syncthreads();

  // long_term[d] = sum_l a[l] * e[l][d]
  float lt = 0.0f;
  for (int l = 0; l < L_SEQ; ++l) lt = fmaf(a_lds[l], e_lds[l][lane], lt);
  __syncthreads();

  // ---- stage 2: ls = [long_term, e[-10:]] ----
  ls_lds[0][lane] = lt;
#pragma unroll
  for (int j = 1; j < LS_LEN; ++j)
    ls_lds[j][lane] = e_lds[L_SEQ - SHORT_LEN + (j - 1)][lane];

  float4 w2r[16];
#pragma unroll
  for (int k = 0; k < 16; ++k) w2r[k] = *(const float4*)&w2[lane * D_EMB + 4 * k];
  const float bias2 = w2b[lane] + b2[lane];
  __syncthreads();

  float s2_val = 0.0f;
  for (int j = 0; j < LS_LEN; ++j) {
    float acc = bias2;
#pragma unroll
    for (int k = 0; k < 16; ++k) {
      float4 lv = *(const float4*)&ls_lds[j][4 * k];
      acc = fmaf(lv.x, w2r[k].x, acc);
      acc = fmaf(lv.y, w2r[k].y, acc);
      acc = fmaf(lv.z, w2r[k].z, acc);
      acc = fmaf(lv.w, w2r[k].w, acc);
    }
    acc = fmaxf(acc, 0.0f);
    float t = wave_sum(acc * u);
    bool msk = (j == 0) ? false : (seq_lds[L_SEQ - SHORT_LEN + (j - 1)] == 0);
    if (lane == j) s2_val = msk ? NEG_INF_F : t;
  }
  {
    float x = (lane < LS_LEN) ? s2_val : -INFINITY;
    float m = wave_max(x);
    float p = (lane < LS_LEN) ? __expf(x - m) : 0.0f;
    float ps = wave_sum(p);
    __syncthreads();  // a_lds reuse
    a_lds[lane] = p / ps;
  }
  __syncthreads();

  float po = 0.0f;
#pragma unroll
  for (int j = 0; j < LS_LEN; ++j) po = fmaf(a_lds[j], ls_lds[j][lane], po);
  if (pooled_f32) pooled_f32[(long)b * D_EMB + lane] = po;
  if (pooled_bf) pooled_bf[(long)b * D_EMB + lane] = (__bf16)po;
}

// fp32 -> bf16, 8 elements per thread, 16B stores.
__global__ __launch_bounds__(256) void cvt_bf16_kernel(
    const float* __restrict__ in, __bf16* __restrict__ out, int n8) {
  int i = blockIdx.x * blockDim.x + threadIdx.x;
  if (i >= n8) return;
  float4 a = ((const float4*)in)[2 * i];
  float4 b = ((const float4*)in)[2 * i + 1];
  bf16x8 v;
  v[0] = (__bf16)a.x; v[1] = (__bf16)a.y; v[2] = (__bf16)a.z; v[3] = (__bf16)a.w;
  v[4] = (__bf16)b.x; v[5] = (__bf16)b.y; v[6] = (__bf16)b.z; v[7] = (__bf16)b.w;
  ((bf16x8*)out)[i] = v;
}

// MFMA scores, ROW-OWNERSHIP decomposition (page-sequential writes).
//   Block (4 waves, LDS=0) owns 16 batch rows x one quarter of the item
//   axis and walks it strictly left->right; waves round-robin consecutive
//   16-item tiles (w, w+4, ...), so all 4 waves stay within the same ~4KB
//   page window of each row. Every output 4KB page is entered exactly ONCE
//   by exactly one block and walked sequentially (= fillBuffer's page
//   behavior, ~200K total page transitions vs ~800K in r4). TLB/UTC theory:
//   r2-r8's 30-130K live scattered pages made most stores pay a translation
//   walk; this shrinks per-block live pages to 16-ish rows x 1 page.
//   Grid = 4*B/16 = 512 = exactly 2 blocks/CU, all resident, no churn.
//   Item quarter (3.2MB) fits each XCD L2, shared by 128 co-resident
//   blocks; nt-stores keep the 800MB write stream from evicting it.
// C/D map (HW-verified): col = lane&15 (batch), row = 4*(lane>>4)+reg (item);
// lane's 4 acc regs = 4 consecutive items -> one dwordx4 nt-store.
__global__ __launch_bounds__(256) void scores_mfma_kernel(
    const __bf16* __restrict__ pooled_bf,  // [B][64]
    const __bf16* __restrict__ item_bf,    // [NI][64]
    float* __restrict__ out, int NI, int n_tiles, int n_rowgrp, int qtiles) {
  const int bid = blockIdx.x;
  const int q = bid / n_rowgrp;     // item quarter
  const int rg = bid % n_rowgrp;    // row group
  const int tid = threadIdx.x;
  const int w = tid >> 6;
  const int l = tid & 63;
  const int lr = l & 15;   // A: item row in tile / B: batch col / C: col
  const int lg = l >> 4;   // k-chunk (8 elems) / C row-group
  const int b0 = rg * 16;  // this block's 16 batch rows

  // B-operand (pooled) fragment: 16 batch rows x 2 k-halves.
  const __bf16* prow = pooled_bf + (size_t)(b0 + lr) * D_EMB + 8 * lg;
  bf16x8 pf0 = *(const bf16x8*)(prow);
  bf16x8 pf1 = *(const bf16x8*)(prow + 32);

  const int t_begin = q * qtiles;
  const int t_end = min(t_begin + qtiles, n_tiles);

  // Wave w walks tiles t_begin+w, +4, ... : the 4 waves cover consecutive
  // tiles, staying within one ~4KB page window per row as they advance.
#pragma unroll 4
  for (int t = t_begin + w; t < t_end; t += 4) {
    const __bf16* brow = item_bf + (size_t)(t * 16 + lr) * D_EMB + 8 * lg;
    bf16x8 a0 = *(const bf16x8*)(brow);
    bf16x8 a1 = *(const bf16x8*)(brow + 32);
    f32x4 acc = {0.f, 0.f, 0.f, 0.f};
    acc = __builtin_amdgcn_mfma_f32_16x16x32_bf16(a0, pf0, acc, 0, 0, 0);
    acc = __builtin_amdgcn_mfma_f32_16x16x32_bf16(a1, pf1, acc, 0, 0, 0);
    float* op = out + (size_t)(b0 + lr) * NI + t * 16 + 4 * lg;
    __builtin_nontemporal_store(acc, (f32x4*)op);
  }
}

// ---------- fallback fp32 scores (round-1 kernel), used if ws too small ----------
__global__ __launch_bounds__(256) void scores_kernel(
    const float* __restrict__ pooled, const float* __restrict__ item_emb,
    float* __restrict__ out, int NI) {
  constexpr int STR = 68;
  __shared__ __align__(16) float poolT[64 * STR];
  __shared__ __align__(16) float itemT[64 * STR];

  const int tid = threadIdx.x;
  const int lane = tid & 63;
  const int b0 = blockIdx.x * 64;
  const int i0 = blockIdx.y * 64;

  for (int r = tid >> 6; r < 64; r += 4) {
    poolT[lane * STR + r] = pooled[(long)(b0 + r) * D_EMB + lane];
    int i = i0 + r;
    itemT[lane * STR + r] = (i < NI) ? item_emb[(long)i * D_EMB + lane] : 0.0f;
  }
  __syncthreads();

  const int tx = tid & 15;
  const int ty = tid >> 4;
  float acc[4][4] = {};

#pragma unroll 8
  for (int d = 0; d < 64; ++d) {
    float4 pv = *(const float4*)&poolT[d * STR + ty * 4];
    float4 iv = *(const float4*)&itemT[d * STR + tx * 4];
    float pva[4] = {pv.x, pv.y, pv.z, pv.w};
    float iva[4] = {iv.x, iv.y, iv.z, iv.w};
#pragma unroll
    for (int m = 0; m < 4; ++m)
#pragma unroll
      for (int n = 0; n < 4; ++n) acc[m][n] = fmaf(pva[m], iva[n], acc[m][n]);
  }

  const int ibase = i0 + tx * 4;
  const long orow = (long)(b0 + ty * 4);
  if (i0 + 63 < NI) {
#pragma unroll
    for (int m = 0; m < 4; ++m) {
      float4 v = make_float4(acc[m][0], acc[m][1], acc[m][2], acc[m][3]);
      *(float4*)&out[(orow + m) * (long)NI + ibase] = v;
    }
  } else {
#pragma unroll
    for (int m = 0; m < 4; ++m)
#pragma unroll
      for (int n = 0; n < 4; ++n)
        if (ibase + n < NI) out[(orow + m) * (long)NI + ibase + n] = acc[m][n];
  }
}

extern "C" void kernel_launch(void* const* d_in, const int* in_sizes, int n_in,
                              void* d_out, int out_size, void* d_ws, size_t ws_size,
                              hipStream_t stream) {
  const int* seq = (const int*)d_in[0];
  const int* user_id = (const int*)d_in[1];
  const float* item_emb = (const float*)d_in[2];
  const float* user_emb = (const float*)d_in[3];
  const float* w1 = (const float*)d_in[4];
  const float* w1b = (const float*)d_in[5];
  const float* b1 = (const float*)d_in[6];
  const float* w2 = (const float*)d_in[7];
  const float* w2b = (const float*)d_in[8];
  const float* b2 = (const float*)d_in[9];
  float* out = (float*)d_out;

  const int B = in_sizes[1];           // 2048
  const int NI = in_sizes[2] / D_EMB;  // 100000

  const size_t item_bf_bytes = (size_t)NI * D_EMB * 2;
  const size_t pooled_bf_bytes = (size_t)B * D_EMB * 2;
  const bool mfma_ok = (ws_size >= item_bf_bytes + pooled_bf_bytes) &&
                       (NI % 16 == 0) && (B % 16 == 0) && (D_EMB == 64);

  if (mfma_ok) {
    __bf16* item_bf = (__bf16*)d_ws;
    __bf16* pooled_bf = (__bf16*)((char*)d_ws + item_bf_bytes);

    const int n8 = NI * D_EMB / 8;
    cvt_bf16_kernel<<<(n8 + 255) / 256, 256, 0, stream>>>(item_emb, item_bf, n8);

    pool_kernel<<<B, 64, 0, stream>>>(seq, user_id, item_emb, user_emb,
                                      w1, w1b, b1, w2, w2b, b2,
                                      (float*)nullptr, pooled_bf);

    const int n_tiles = NI / 16;                               // 6250
    const int n_rowgrp = B / 16;                               // 128
    const int qtiles = (n_tiles + N_QUARTERS - 1) / N_QUARTERS; // 1563
    scores_mfma_kernel<<<N_QUARTERS * n_rowgrp, 256, 0, stream>>>(
        pooled_bf, item_bf, out, NI, n_tiles, n_rowgrp, qtiles);
  } else {
    float* pooled = (float*)d_ws;  // B * 64 floats
    pool_kernel<<<B, 64, 0, stream>>>(seq, user_id, item_emb, user_emb,
                                      w1, w1b, b1, w2, w2b, b2,
                                      pooled, (__bf16*)nullptr);
    dim3 grid(B / 64, (NI + 63) / 64);
    scores_kernel<<<grid, 256, 0, stream>>>(pooled, item_emb, out, NI);
  }
}